// Round 1
// 189.980 us; speedup vs baseline: 1.1185x; 1.1185x over previous
//
#include <hip/hip_runtime.h>
#include <math.h>

// ---------------------------------------------------------------------------
// HierarchicalVAE, MI355X (gfx950), fp32 — R7: batch-in-lanes restructure.
// R6 post-mortem: 128 per-row mega-blocks -> half the CUs idle, 2 waves/SIMD,
// ~21 barrier segments each stalling ~15K cycles on cold weight loads
// (VALUBusy 5.4%, occupancy 10.8%, latency-bound).
// R7: 9 small stage kernels; lane = batch row (128 rows = 2 wave halves),
// block = output column (x row-half), 8 waves = 8 K-slices. Weights become
// wave-uniform scalar loads amortized over 64 rows; activations live in a
// transposed [feat][128] workspace with coalesced 256B accesses. z is
// recomputed in dec1/ref1 from mu_T/lv_T/eps (identical fp32 expression).
//
// Output layout (flat f32): rendered@0, mu@100352, logvar@108544,
// cp@116736, widths@124928, alphas@125184.
// ---------------------------------------------------------------------------

#define O_MU  100352
#define O_LV  108544
#define O_CP  116736
#define O_WD  124928
#define O_AL  125184

// workspace float offsets (total 289280 floats = 1.16 MB)
#define W_H1   0        // h1_T  [256][128]
#define W_HE   32768    // he_T  [256][128]
#define W_MUT  65536    // mu_T  [64][128]
#define W_LVT  73728    // lv_T  [64][128]
#define W_D1   81920    // d1_T  [512][128]
#define W_H2   147456   // h2_T  [512][128]
#define W_PN   212992   // pn_T  [28][128]
#define W_R1   216576   // r1_T  [512][128]
#define W_PT   282112   // P_T   [52][128]
#define W_WA   288768   // wa_T  [4][128]  (w0,w1,a0,a1)

__device__ __forceinline__ float leaky(float x) { return x >= 0.f ? x : 0.2f * x; }
__device__ __forceinline__ float seluf(float x) {
    const float s = 1.0507009873554805f, a = 1.6732632423543772f;
    return x > 0.f ? s * x : s * (a * expm1f(x));
}
__device__ __forceinline__ float sigm(float x) { return 1.f / (1.f + expf(-x)); }

// ---- enc1: h1_T = leaky(x @ enc_w1 + b). grid 512: j=bid>>1, h=bid&1.
__global__ __launch_bounds__(512)
void enc1_k(const float* __restrict__ x, const float* __restrict__ w,
            const float* __restrict__ b, float* __restrict__ outT) {
    __shared__ float part[8][64];
    const int j = blockIdx.x >> 1, h = blockIdx.x & 1;
    const int tid = threadIdx.x, lane = tid & 63, ks = tid >> 6;
    const int r = h * 64 + lane;
    const float* __restrict__ xr = x + r * 784;   // per-lane row of x (L1-resident lines)
    float acc = 0.f;
    const int k0 = ks * 98;
#pragma unroll 7
    for (int i = 0; i < 98; i++)
        acc = fmaf(xr[k0 + i], w[(k0 + i) * 256 + j], acc);
    part[ks][lane] = acc;
    __syncthreads();
    if (tid < 64) {
        float s = b[j];
#pragma unroll
        for (int q = 0; q < 8; q++) s += part[q][tid];
        outT[j * 128 + h * 64 + tid] = leaky(s);
    }
}

// ---- enc2: he_T = leaky(h1_T^T @ enc_w2 + b). grid 512.
__global__ __launch_bounds__(512)
void enc2_k(const float* __restrict__ inT, const float* __restrict__ w,
            const float* __restrict__ b, float* __restrict__ outT) {
    __shared__ float part[8][64];
    const int j = blockIdx.x >> 1, h = blockIdx.x & 1;
    const int tid = threadIdx.x, lane = tid & 63, ks = tid >> 6;
    const int r = h * 64 + lane;
    float acc = 0.f;
    const int k0 = ks * 32;
#pragma unroll 8
    for (int i = 0; i < 32; i++)
        acc = fmaf(inT[(k0 + i) * 128 + r], w[(k0 + i) * 256 + j], acc);
    part[ks][lane] = acc;
    __syncthreads();
    if (tid < 64) {
        float s = b[j];
#pragma unroll
        for (int q = 0; q < 8; q++) s += part[q][tid];
        outT[j * 128 + h * 64 + tid] = leaky(s);
    }
}

// ---- mu|lv: grid 256: meta=bid>>1 (head=meta>>6, col=meta&63), h=bid&1.
__global__ __launch_bounds__(512)
void mulv_k(const float* __restrict__ heT,
            const float* __restrict__ mu_w, const float* __restrict__ mu_b,
            const float* __restrict__ lv_w, const float* __restrict__ lv_b,
            float* __restrict__ muT, float* __restrict__ lvT,
            float* __restrict__ out) {
    __shared__ float part[8][64];
    const int meta = blockIdx.x >> 1, h = blockIdx.x & 1;
    const int head = meta >> 6, col = meta & 63;
    const float* __restrict__ w = head ? lv_w : mu_w;
    const int tid = threadIdx.x, lane = tid & 63, ks = tid >> 6;
    const int r = h * 64 + lane;
    float acc = 0.f;
    const int k0 = ks * 32;
#pragma unroll 8
    for (int i = 0; i < 32; i++)
        acc = fmaf(heT[(k0 + i) * 128 + r], w[(k0 + i) * 64 + col], acc);
    part[ks][lane] = acc;
    __syncthreads();
    if (tid < 64) {
        float s = (head ? lv_b : mu_b)[col];
#pragma unroll
        for (int q = 0; q < 8; q++) s += part[q][tid];
        const int rr = h * 64 + tid;
        (head ? lvT : muT)[col * 128 + rr] = s;
        out[(head ? O_LV : O_MU) + rr * 64 + col] = s;
    }
}

// ---- dec1: d1_T = selu(z @ dec_w1 + b), z recomputed from mu/lv/eps.
// grid 512: jpair=bid>>1 (2 cols), h=bid&1. slice 8.
__global__ __launch_bounds__(512)
void dec1_k(const float* __restrict__ muT, const float* __restrict__ lvT,
            const float* __restrict__ eps, const float* __restrict__ w,
            const float* __restrict__ b, float* __restrict__ outT) {
    __shared__ float part[8][2][64];
    const int j0 = (blockIdx.x >> 1) * 2, h = blockIdx.x & 1;
    const int tid = threadIdx.x, lane = tid & 63, ks = tid >> 6;
    const int r = h * 64 + lane;
    float a0 = 0.f, a1 = 0.f;
    const int k0 = ks * 8;
#pragma unroll
    for (int i = 0; i < 8; i++) {
        const int k = k0 + i;
        float zv = fmaf(eps[r * 64 + k], expf(0.5f * lvT[k * 128 + r]), muT[k * 128 + r]);
        a0 = fmaf(zv, w[k * 512 + j0],     a0);
        a1 = fmaf(zv, w[k * 512 + j0 + 1], a1);
    }
    part[ks][0][lane] = a0; part[ks][1][lane] = a1;
    __syncthreads();
    if (tid < 128) {
        const int c = tid >> 6, ll = tid & 63;
        float s = b[j0 + c];
#pragma unroll
        for (int q = 0; q < 8; q++) s += part[q][c][ll];
        outT[(j0 + c) * 128 + h * 64 + ll] = seluf(s);
    }
}

// ---- dec2: h2_T = selu(d1 @ dec_w2 + b). grid 512, 2 cols, slice 64.
__global__ __launch_bounds__(512)
void dec2_k(const float* __restrict__ inT, const float* __restrict__ w,
            const float* __restrict__ b, float* __restrict__ outT) {
    __shared__ float part[8][2][64];
    const int j0 = (blockIdx.x >> 1) * 2, h = blockIdx.x & 1;
    const int tid = threadIdx.x, lane = tid & 63, ks = tid >> 6;
    const int r = h * 64 + lane;
    float a0 = 0.f, a1 = 0.f;
    const int k0 = ks * 64;
#pragma unroll 4
    for (int i = 0; i < 64; i++) {
        const float v = inT[(k0 + i) * 128 + r];
        a0 = fmaf(v, w[(k0 + i) * 512 + j0],     a0);
        a1 = fmaf(v, w[(k0 + i) * 512 + j0 + 1], a1);
    }
    part[ks][0][lane] = a0; part[ks][1][lane] = a1;
    __syncthreads();
    if (tid < 128) {
        const int c = tid >> 6, ll = tid & 63;
        float s = b[j0 + c];
#pragma unroll
        for (int q = 0; q < 8; q++) s += part[q][c][ll];
        outT[(j0 + c) * 128 + h * 64 + ll] = seluf(s);
    }
}

// ---- heads: cp->pn_T (tanh), wd/al->out + wa_T. grid 64: j=bid>>1, h=bid&1.
__global__ __launch_bounds__(512)
void heads_k(const float* __restrict__ h2T,
             const float* __restrict__ cp_w, const float* __restrict__ cp_b,
             const float* __restrict__ wd_w, const float* __restrict__ wd_b,
             const float* __restrict__ al_w, const float* __restrict__ al_b,
             float* __restrict__ pnT, float* __restrict__ waT,
             float* __restrict__ out) {
    __shared__ float part[8][64];
    const int j = blockIdx.x >> 1, h = blockIdx.x & 1;
    const float* __restrict__ w; int ldw, col;
    if (j < 28)      { w = cp_w; ldw = 28; col = j; }
    else if (j < 30) { w = wd_w; ldw = 2;  col = j - 28; }
    else             { w = al_w; ldw = 2;  col = j - 30; }
    const int tid = threadIdx.x, lane = tid & 63, ks = tid >> 6;
    const int r = h * 64 + lane;
    float acc = 0.f;
    const int k0 = ks * 64;
#pragma unroll 8
    for (int i = 0; i < 64; i++)
        acc = fmaf(h2T[(k0 + i) * 128 + r], w[(k0 + i) * ldw + col], acc);
    part[ks][lane] = acc;
    __syncthreads();
    if (tid < 64) {
        float s = 0.f;
#pragma unroll
        for (int q = 0; q < 8; q++) s += part[q][tid];
        const int rr = h * 64 + tid;
        if (j < 28) {
            pnT[j * 128 + rr] = tanhf(s + cp_b[col]);
        } else if (j < 30) {
            float v = fmaf(sigm(s + wd_b[col]), 2.f, 1.f);
            out[O_WD + rr * 2 + col] = v; waT[col * 128 + rr] = v;
        } else {
            float v = sigm(s + al_b[col]);
            out[O_AL + rr * 2 + col] = v; waT[(2 + col) * 128 + rr] = v;
        }
    }
}

// ---- ref1: r1_T = selu(h_in @ ref_w1 + b); h_in = [z(64) | pn(28)].
// grid 512, 2 cols, slice 12 (guard k<92).
__global__ __launch_bounds__(512)
void ref1_k(const float* __restrict__ muT, const float* __restrict__ lvT,
            const float* __restrict__ eps, const float* __restrict__ pnT,
            const float* __restrict__ w, const float* __restrict__ b,
            float* __restrict__ outT) {
    __shared__ float part[8][2][64];
    const int j0 = (blockIdx.x >> 1) * 2, h = blockIdx.x & 1;
    const int tid = threadIdx.x, lane = tid & 63, ks = tid >> 6;
    const int r = h * 64 + lane;
    float a0 = 0.f, a1 = 0.f;
#pragma unroll
    for (int i = 0; i < 12; i++) {
        const int k = ks * 12 + i;
        if (k < 92) {
            float v = (k < 64)
                ? fmaf(eps[r * 64 + k], expf(0.5f * lvT[k * 128 + r]), muT[k * 128 + r])
                : pnT[(k - 64) * 128 + r];
            a0 = fmaf(v, w[k * 512 + j0],     a0);
            a1 = fmaf(v, w[k * 512 + j0 + 1], a1);
        }
    }
    part[ks][0][lane] = a0; part[ks][1][lane] = a1;
    __syncthreads();
    if (tid < 128) {
        const int c = tid >> 6, ll = tid & 63;
        float s = b[j0 + c];
#pragma unroll
        for (int q = 0; q < 8; q++) s += part[q][c][ll];
        outT[(j0 + c) * 128 + h * 64 + ll] = seluf(s);
    }
}

// ---- ref2: P_T = tanh(r1 @ ref_w2 + b)*12 + 14. grid 104: j=bid>>1, h=bid&1.
__global__ __launch_bounds__(512)
void ref2_k(const float* __restrict__ r1T, const float* __restrict__ w,
            const float* __restrict__ b, float* __restrict__ PT) {
    __shared__ float part[8][64];
    const int j = blockIdx.x >> 1, h = blockIdx.x & 1;
    const int tid = threadIdx.x, lane = tid & 63, ks = tid >> 6;
    const int r = h * 64 + lane;
    float acc = 0.f;
    const int k0 = ks * 64;
#pragma unroll 8
    for (int i = 0; i < 64; i++)
        acc = fmaf(r1T[(k0 + i) * 128 + r], w[(k0 + i) * 52 + j], acc);
    part[ks][lane] = acc;
    __syncthreads();
    if (tid < 64) {
        float s = b[j];
#pragma unroll
        for (int q = 0; q < 8; q++) s += part[q][tid];
        PT[j * 128 + h * 64 + tid] = fmaf(tanhf(s), 12.f, 14.f);
    }
}

// ---- raster: grid 896 = 128 rows x 7 pixel-chunks (112 px x 4 AA each).
__global__ __launch_bounds__(512)
void raster_k(const float* __restrict__ PT, const float* __restrict__ waT,
              float* __restrict__ out) {
    __shared__ float sP[56];
    __shared__ float sWA[4];
    __shared__ float sQ[128];
    const int bid = blockIdx.x;
    const int row = bid / 7, chunk = bid - row * 7;
    const int tid = threadIdx.x;
    if (tid < 52) sP[tid] = PT[tid * 128 + row];
    if (tid >= 64 && tid < 68) sWA[tid - 64] = waT[(tid - 64) * 128 + row];
    __syncthreads();
    if (chunk == 0 && tid < 64) {
        const int idx = tid, p = idx >> 5, rest = idx & 31;
        const int s = rest >> 3, kk = (rest >> 1) & 3, d = idx & 1;
        out[O_CP + row * 64 + idx] = sP[p * 26 + (3 * s + kk) * 2 + d];
    }
    if (tid < 128) {
        const int idx = tid, p = idx >> 6, s = (idx >> 4) & 3, ti = (idx >> 1) & 7, d = idx & 1;
        const float t = (float)ti / 7.0f, mt = 1.0f - t;
        const float c0 = mt * mt * mt, c1 = 3.f * mt * mt * t;
        const float c2 = 3.f * mt * t * t, c3 = t * t * t;
        const float* base = sP + p * 26 + 6 * s + d;
        sQ[idx] = c0 * base[0] + c1 * base[2] + c2 * base[4] + c3 * base[6];
    }
    __syncthreads();
    if (tid < 448) {
        const int pixel = chunk * 112 + (tid >> 2), sub = tid & 3;
        const int py = pixel / 28, px = pixel - py * 28;
        const float sy = ((float)(2 * py + (sub >> 1)) + 0.5f) * 0.5f;
        const float sx = ((float)(2 * px + (sub & 1)) + 0.5f) * 0.5f;
        const float2* __restrict__ sQ2 = (const float2*)sQ;
        float img = 1.0f;
#pragma unroll
        for (int p = 0; p < 2; p++) {
            float dmin2 = 1e30f;
            int cnt = 0;
            float2 cur = sQ2[p * 32];
            bool bp = cur.y > sy;
#pragma unroll
            for (int m = 0; m < 32; m++) {
                float2 nxt = sQ2[p * 32 + ((m + 1) & 31)];
                float dx = sx - cur.x;
                float dy = sy - cur.y;
                dmin2 = fminf(dmin2, fmaf(dx, dx, dy * dy));
                bool bn = nxt.y > sy;
                float den = nxt.y - cur.y + 1e-8f;
                float lhs = dx * den;
                float rhs = dy * (nxt.x - cur.x);
                if ((bp != bn) && ((lhs < rhs) == (den > 0.0f))) cnt++;
                cur = nxt;
                bp = bn;
            }
            float dist = sqrtf(dmin2);
            float stroke = fminf(fmaxf(fmaf(sWA[p], 0.5f, 0.5f) - dist, 0.f), 1.f);
            float cov = fmaxf((float)(cnt & 1), stroke);
            img *= fmaf(-sWA[2 + p], cov, 1.0f);
        }
        img += __shfl_xor(img, 1);
        img += __shfl_xor(img, 2);
        if (sub == 0) out[row * 784 + pixel] = 1.0f - 0.25f * img;
    }
}

extern "C" void kernel_launch(void* const* d_in, const int* in_sizes, int n_in,
                              void* d_out, int out_size, void* d_ws, size_t ws_size,
                              hipStream_t stream) {
    const float* x      = (const float*)d_in[0];
    const float* eps    = (const float*)d_in[1];
    const float* enc_w1 = (const float*)d_in[2];
    const float* enc_b1 = (const float*)d_in[3];
    const float* enc_w2 = (const float*)d_in[4];
    const float* enc_b2 = (const float*)d_in[5];
    const float* mu_w   = (const float*)d_in[6];
    const float* mu_b   = (const float*)d_in[7];
    const float* lv_w   = (const float*)d_in[8];
    const float* lv_b   = (const float*)d_in[9];
    const float* dec_w1 = (const float*)d_in[10];
    const float* dec_b1 = (const float*)d_in[11];
    const float* dec_w2 = (const float*)d_in[12];
    const float* dec_b2 = (const float*)d_in[13];
    const float* cp_w   = (const float*)d_in[14];
    const float* cp_b   = (const float*)d_in[15];
    const float* ref_w1 = (const float*)d_in[16];
    const float* ref_b1 = (const float*)d_in[17];
    const float* ref_w2 = (const float*)d_in[18];
    const float* ref_b2 = (const float*)d_in[19];
    const float* wd_w   = (const float*)d_in[20];
    const float* wd_b   = (const float*)d_in[21];
    const float* al_w   = (const float*)d_in[22];
    const float* al_b   = (const float*)d_in[23];

    float* out = (float*)d_out;
    float* ws  = (float*)d_ws;   // needs 289280 floats = 1.16 MB

    enc1_k <<<512, 512, 0, stream>>>(x, enc_w1, enc_b1, ws + W_H1);
    enc2_k <<<512, 512, 0, stream>>>(ws + W_H1, enc_w2, enc_b2, ws + W_HE);
    mulv_k <<<256, 512, 0, stream>>>(ws + W_HE, mu_w, mu_b, lv_w, lv_b,
                                     ws + W_MUT, ws + W_LVT, out);
    dec1_k <<<512, 512, 0, stream>>>(ws + W_MUT, ws + W_LVT, eps,
                                     dec_w1, dec_b1, ws + W_D1);
    dec2_k <<<512, 512, 0, stream>>>(ws + W_D1, dec_w2, dec_b2, ws + W_H2);
    heads_k<<<64, 512, 0, stream>>>(ws + W_H2, cp_w, cp_b, wd_w, wd_b, al_w, al_b,
                                    ws + W_PN, ws + W_WA, out);
    ref1_k <<<512, 512, 0, stream>>>(ws + W_MUT, ws + W_LVT, eps, ws + W_PN,
                                     ref_w1, ref_b1, ws + W_R1);
    ref2_k <<<104, 512, 0, stream>>>(ws + W_R1, ref_w2, ref_b2, ws + W_PT);
    raster_k<<<896, 512, 0, stream>>>(ws + W_PT, ws + W_WA, out);
}